// Round 1
// baseline (34105.377 us; speedup 1.0000x reference)
//
#include <hip/hip_runtime.h>

// ---------------- constants ----------------
static constexpr int B_   = 128;
static constexpr int LC_  = 256;
static constexpr int LE_  = 257;
static constexpr int H_   = 512;
static constexpr size_t HB_ = (size_t)512 * 128;   // one (feature,batch) plane

// ---------------- workspace layout (bytes) ----------------
static constexpr size_t OFF_ENC    = 0;                                   // bf16 [B][LC][1024]
static constexpr size_t SZ_ENC     = (size_t)128 * 256 * 1024 * 2;        // 64 MiB
static constexpr size_t OFF_WIHFT  = OFF_ENC + SZ_ENC;                    // f32 [128][2048]
static constexpr size_t OFF_WIHBT  = OFF_WIHFT + (size_t)128 * 2048 * 4;
static constexpr size_t OFF_XDEC   = OFF_WIHBT + (size_t)128 * 2048 * 4;  // dec_Wih cols 0..127 ^T
static constexpr size_t OFF_WATTNT = OFF_XDEC + (size_t)128 * 2048 * 4;   // f32 [1024][512]
static constexpr size_t OFF_HENC   = OFF_WATTNT + (size_t)1024 * 512 * 4; // [2dir][2par][512][128]
static constexpr size_t OFF_CENC   = OFF_HENC + 4 * HB_ * 4;              // [2dir][512][128]
static constexpr size_t OFF_HDEC   = OFF_CENC + 2 * HB_ * 4;              // [2par][512][128]
static constexpr size_t OFF_CDEC   = OFF_HDEC + 2 * HB_ * 4;              // [512][128]
static constexpr size_t OFF_TOUT   = OFF_CDEC + HB_ * 4;                  // [2par][512][128]
static constexpr size_t OFF_U      = OFF_TOUT + 2 * HB_ * 4;              // [1024][128]
static constexpr size_t OFF_CTX    = OFF_U + (size_t)1024 * 128 * 4;      // [1024][128]
static constexpr size_t OFF_SC     = OFF_CTX + (size_t)1024 * 128 * 4;    // scores [128][256]
static constexpr size_t OFF_MD     = OFF_SC + (size_t)128 * 256 * 4;      // M[128] D[128] pgen[128]

// ---------------- helpers ----------------
__device__ __forceinline__ float sigm(float x) { return 1.f / (1.f + expf(-x)); }
__device__ __forceinline__ unsigned short f2bf(float f) {
  unsigned u = __float_as_uint(f);
  u += 0x7fffu + ((u >> 16) & 1u);
  return (unsigned short)(u >> 16);
}
__device__ __forceinline__ float bfl(unsigned w) { return __uint_as_float(w << 16); }
__device__ __forceinline__ float bfh(unsigned w) { return __uint_as_float(w & 0xffff0000u); }

// ---------------- preprocessing: transposes ----------------
__global__ __launch_bounds__(256) void k_pre(const float* __restrict__ wihF,
                                             const float* __restrict__ wihB,
                                             const float* __restrict__ dWih,
                                             const float* __restrict__ Wattn,
                                             float* __restrict__ ws) {
  float* WT_F = (float*)((char*)ws + OFF_WIHFT);
  float* WT_B = (float*)((char*)ws + OFF_WIHBT);
  float* XD   = (float*)((char*)ws + OFF_XDEC);
  float* WAT  = (float*)((char*)ws + OFF_WATTNT);
  int stride = gridDim.x * blockDim.x;
  int i0 = blockIdx.x * blockDim.x + threadIdx.x;
  for (int x = i0; x < 128 * 2048; x += stride) {
    int v = x >> 11, n = x & 2047;
    WT_F[x] = wihF[n * 128 + v];
    WT_B[x] = wihB[n * 128 + v];
    XD[x]   = dWih[n * 640 + v];
  }
  for (int x = i0; x < 1024 * 512; x += stride) {
    int j = x >> 9, i2 = x & 511;
    WAT[x] = Wattn[i2 * 1024 + j];
  }
}

// ---------------- encoder step (both directions) ----------------
__global__ __launch_bounds__(512) void k_enc(const float* __restrict__ WhhF,
                                             const float* __restrict__ WhhB,
                                             const float* __restrict__ bF,
                                             const float* __restrict__ bB,
                                             const int* __restrict__ C_idx,
                                             float* __restrict__ ws, int t) {
  int p = blockIdx.x * 512 + threadIdx.x;    // 131072 = 2dir * 512j * 128b
  int b = p & 127;
  int j = (p >> 7) & 511;
  int dir = p >> 16;
  int jj = __builtin_amdgcn_readfirstlane(j);
  int dd = __builtin_amdgcn_readfirstlane(dir);
  const float* Whh  = dd ? WhhB : WhhF;
  const float* bias = dd ? bB : bF;
  const float* WihT = (const float*)((char*)ws + (dd ? OFF_WIHBT : OFF_WIHFT));
  int l = dd ? (LC_ - 1 - t) : t;
  int cidx = C_idx[b * LC_ + l];
  int par = t & 1;
  const float* hp = (const float*)((char*)ws + OFF_HENC) + (size_t)(dir * 2 + (par ^ 1)) * HB_ + b;

  const float* w0 = Whh + (size_t)jj * 512;
  const float* w1 = Whh + (size_t)(512 + jj) * 512;
  const float* w2 = Whh + (size_t)(1024 + jj) * 512;
  const float* w3 = Whh + (size_t)(1536 + jj) * 512;
  float a0 = bias[jj]        + WihT[(size_t)cidx * 2048 + jj];
  float a1 = bias[512 + jj]  + WihT[(size_t)cidx * 2048 + 512 + jj];
  float a2 = bias[1024 + jj] + WihT[(size_t)cidx * 2048 + 1024 + jj];
  float a3 = bias[1536 + jj] + WihT[(size_t)cidx * 2048 + 1536 + jj];
  for (int k = 0; k < 512; k += 4) {
    float4 W0 = *(const float4*)(w0 + k);
    float4 W1 = *(const float4*)(w1 + k);
    float4 W2 = *(const float4*)(w2 + k);
    float4 W3 = *(const float4*)(w3 + k);
    float h0 = hp[(size_t)k * 128], h1 = hp[(size_t)(k + 1) * 128];
    float h2 = hp[(size_t)(k + 2) * 128], h3 = hp[(size_t)(k + 3) * 128];
    a0 += W0.x * h0 + W0.y * h1 + W0.z * h2 + W0.w * h3;
    a1 += W1.x * h0 + W1.y * h1 + W1.z * h2 + W1.w * h3;
    a2 += W2.x * h0 + W2.y * h1 + W2.z * h2 + W2.w * h3;
    a3 += W3.x * h0 + W3.y * h1 + W3.z * h2 + W3.w * h3;
  }
  float ig = sigm(a0), fg = sigm(a1), gg = tanhf(a2), og = sigm(a3);
  float* cp = (float*)((char*)ws + OFF_CENC) + (size_t)dir * HB_ + (size_t)j * 128 + b;
  float c = fg * (*cp) + ig * gg;
  *cp = c;
  float h = og * tanhf(c);
  ((float*)((char*)ws + OFF_HENC))[(size_t)(dir * 2 + par) * HB_ + (size_t)j * 128 + b] = h;
  ((unsigned short*)((char*)ws + OFF_ENC))[((size_t)b * LC_ + l) * 1024 + dir * 512 + j] = f2bf(h);
}

// ---------------- h0/c0 ----------------
__global__ __launch_bounds__(512) void k_h0c0(const float* __restrict__ Wh,
                                              const float* __restrict__ Wc,
                                              float* __restrict__ ws) {
  int p = blockIdx.x * 512 + threadIdx.x;   // 131072 = 2sel * 512n * 128b
  int b = p & 127;
  int n = (p >> 7) & 511;
  int sel = p >> 16;
  int nn = __builtin_amdgcn_readfirstlane(n);
  int ss = __builtin_amdgcn_readfirstlane(sel);
  const float* W = (ss ? Wc : Wh) + (size_t)nn * 1024;
  const float* hf = (const float*)((char*)ws + OFF_HENC) + (size_t)1 * HB_ + b;  // dir0 par1
  const float* hb = (const float*)((char*)ws + OFF_HENC) + (size_t)3 * HB_ + b;  // dir1 par1
  float acc = 0.f;
  for (int k = 0; k < 512; k += 4) {
    float4 Wa = *(const float4*)(W + k);
    float4 Wb = *(const float4*)(W + 512 + k);
    acc += Wa.x * hf[(size_t)k * 128] + Wa.y * hf[(size_t)(k + 1) * 128]
         + Wa.z * hf[(size_t)(k + 2) * 128] + Wa.w * hf[(size_t)(k + 3) * 128];
    acc += Wb.x * hb[(size_t)k * 128] + Wb.y * hb[(size_t)(k + 1) * 128]
         + Wb.z * hb[(size_t)(k + 2) * 128] + Wb.w * hb[(size_t)(k + 3) * 128];
  }
  float* dst = (float*)((char*)ws + (ss ? OFF_CDEC : OFF_HDEC));
  dst[(size_t)n * 128 + b] = acc;
}

// ---------------- S4: vocab softmax at target + copy mass + nll ----------------
__device__ void s4_body(float* __restrict__ ws, float* __restrict__ out,
                        const float* __restrict__ Wvocab, const int* __restrict__ E_idx,
                        const int* __restrict__ C_idx, int b, int t) {
  __shared__ float to[516];
  __shared__ float lgp[128][4];
  __shared__ float lg[128];
  __shared__ float red2[8];
  __shared__ float mx_s[2];
  int tau = threadIdx.x;
  const float* TO = (const float*)((char*)ws + OFF_TOUT) + (size_t)(t & 1) * HB_;
  to[tau + (tau >> 7)] = TO[(size_t)tau * 128 + b];
  __syncthreads();
  int v = tau >> 2, seg = tau & 3;
  const float* wv = Wvocab + (size_t)v * 512 + seg * 128;
  const float* tp = &to[seg * 128 + seg];
  float part = 0.f;
#pragma unroll 8
  for (int i = 0; i < 128; ++i) part += tp[i] * wv[i];
  lgp[v][seg] = part;
  __syncthreads();
  if (tau < 128) lg[tau] = lgp[tau][0] + lgp[tau][1] + lgp[tau][2] + lgp[tau][3];
  __syncthreads();
  if (tau < 64) {
    float m2 = fmaxf(lg[tau], lg[tau + 64]);
    for (int o = 32; o; o >>= 1) m2 = fmaxf(m2, __shfl_xor(m2, o));
    float e = expf(lg[tau] - m2) + expf(lg[tau + 64] - m2);
    for (int o = 32; o; o >>= 1) e += __shfl_xor(e, o);
    if (tau == 0) { mx_s[0] = m2; mx_s[1] = e; }
  }
  const float* MD = (const float*)((char*)ws + OFF_MD);
  float Mb = MD[b], Db = MD[128 + b], pg = MD[256 + b];
  int tgt = E_idx[b * LE_ + t];
  float cm = 0.f;
  if (tau < 256) {
    float s = ((const float*)((char*)ws + OFF_SC))[b * 256 + tau];
    if (C_idx[b * 256 + tau] == tgt) cm = expf(s - Mb);
  }
  for (int o = 32; o; o >>= 1) cm += __shfl_xor(cm, o);
  if ((tau & 63) == 0) red2[tau >> 6] = cm;
  __syncthreads();
  if (tau == 0) {
    float mass = (red2[0] + red2[1] + red2[2] + red2[3]) / Db;
    float gen_tgt = expf(lg[tgt] - mx_s[0]) / mx_s[1];
    float prob = pg * gen_tgt + (1.f - pg) * mass;
    out[b * 256 + (t - 1)] = (tgt == 0) ? 0.f : -logf(prob);
  }
}

// ---------------- decoder gates (+ S4 of previous step) ----------------
__global__ __launch_bounds__(512) void k_dgates(const float* __restrict__ dWih,
                                                const float* __restrict__ dWhh,
                                                const float* __restrict__ db,
                                                const float* __restrict__ Wvocab,
                                                const int* __restrict__ E_idx,
                                                const int* __restrict__ C_idx,
                                                float* __restrict__ ws,
                                                float* __restrict__ out, int t) {
  int tau = threadIdx.x;
  if (blockIdx.x >= 256) {
    if (t > 0) s4_body(ws, out, Wvocab, E_idx, C_idx, blockIdx.x - 256, t);
    return;
  }
  __shared__ float part[4][256];
  int kh = tau >> 8, q = tau & 255;
  int pp = blockIdx.x * 256 + q;        // 65536 = 512j * 128b
  int b = pp & 127, j = pp >> 7;
  int jj = __builtin_amdgcn_readfirstlane(j);
  int pr = t & 1;
  float a0 = 0.f, a1 = 0.f, a2 = 0.f, a3 = 0.f;
  if (kh == 0) {   // prev_out part of dec_Wih (cols 128..639)
    const float* w0 = dWih + (size_t)jj * 640 + 128;
    const float* w1 = dWih + (size_t)(512 + jj) * 640 + 128;
    const float* w2 = dWih + (size_t)(1024 + jj) * 640 + 128;
    const float* w3 = dWih + (size_t)(1536 + jj) * 640 + 128;
    const float* po = (const float*)((char*)ws + OFF_TOUT) + (size_t)pr * HB_ + b;
    for (int k = 0; k < 512; k += 4) {
      float4 W0 = *(const float4*)(w0 + k);
      float4 W1 = *(const float4*)(w1 + k);
      float4 W2 = *(const float4*)(w2 + k);
      float4 W3 = *(const float4*)(w3 + k);
      float h0 = po[(size_t)k * 128], h1 = po[(size_t)(k + 1) * 128];
      float h2 = po[(size_t)(k + 2) * 128], h3 = po[(size_t)(k + 3) * 128];
      a0 += W0.x * h0 + W0.y * h1 + W0.z * h2 + W0.w * h3;
      a1 += W1.x * h0 + W1.y * h1 + W1.z * h2 + W1.w * h3;
      a2 += W2.x * h0 + W2.y * h1 + W2.z * h2 + W2.w * h3;
      a3 += W3.x * h0 + W3.y * h1 + W3.z * h2 + W3.w * h3;
    }
  } else {         // h part (dec_Whh)
    const float* w0 = dWhh + (size_t)jj * 512;
    const float* w1 = dWhh + (size_t)(512 + jj) * 512;
    const float* w2 = dWhh + (size_t)(1024 + jj) * 512;
    const float* w3 = dWhh + (size_t)(1536 + jj) * 512;
    const float* hp = (const float*)((char*)ws + OFF_HDEC) + (size_t)pr * HB_ + b;
    for (int k = 0; k < 512; k += 4) {
      float4 W0 = *(const float4*)(w0 + k);
      float4 W1 = *(const float4*)(w1 + k);
      float4 W2 = *(const float4*)(w2 + k);
      float4 W3 = *(const float4*)(w3 + k);
      float h0 = hp[(size_t)k * 128], h1 = hp[(size_t)(k + 1) * 128];
      float h2 = hp[(size_t)(k + 2) * 128], h3 = hp[(size_t)(k + 3) * 128];
      a0 += W0.x * h0 + W0.y * h1 + W0.z * h2 + W0.w * h3;
      a1 += W1.x * h0 + W1.y * h1 + W1.z * h2 + W1.w * h3;
      a2 += W2.x * h0 + W2.y * h1 + W2.z * h2 + W2.w * h3;
      a3 += W3.x * h0 + W3.y * h1 + W3.z * h2 + W3.w * h3;
    }
    part[0][q] = a0; part[1][q] = a1; part[2][q] = a2; part[3][q] = a3;
  }
  __syncthreads();
  if (kh == 0) {
    int xid = E_idx[b * LE_ + t];
    const float* xg = (const float*)((char*)ws + OFF_XDEC) + (size_t)xid * 2048;
    float g0 = a0 + part[0][q] + db[jj]        + xg[jj];
    float g1 = a1 + part[1][q] + db[512 + jj]  + xg[512 + jj];
    float g2 = a2 + part[2][q] + db[1024 + jj] + xg[1024 + jj];
    float g3 = a3 + part[3][q] + db[1536 + jj] + xg[1536 + jj];
    float ig = sigm(g0), fg = sigm(g1), gg = tanhf(g2), og = sigm(g3);
    float* cp = (float*)((char*)ws + OFF_CDEC) + (size_t)j * 128 + b;
    float c = fg * (*cp) + ig * gg;
    *cp = c;
    ((float*)((char*)ws + OFF_HDEC))[(size_t)(pr ^ 1) * HB_ + (size_t)j * 128 + b] = og * tanhf(c);
  }
}

// ---------------- u = Wattn^T h ----------------
__global__ __launch_bounds__(512) void k_u(const float* __restrict__ unused,
                                           float* __restrict__ ws, int t) {
  int p = blockIdx.x * 512 + threadIdx.x;   // 131072 = 1024j * 128b
  int b = p & 127, j = p >> 7;
  int jj = __builtin_amdgcn_readfirstlane(j);
  const float* w = (const float*)((char*)ws + OFF_WATTNT) + (size_t)jj * 512;
  const float* hp = (const float*)((char*)ws + OFF_HDEC) + (size_t)((t & 1) ^ 1) * HB_ + b;
  float acc = 0.f;
  for (int k = 0; k < 512; k += 4) {
    float4 W = *(const float4*)(w + k);
    acc += W.x * hp[(size_t)k * 128] + W.y * hp[(size_t)(k + 1) * 128]
         + W.z * hp[(size_t)(k + 2) * 128] + W.w * hp[(size_t)(k + 3) * 128];
  }
  ((float*)((char*)ws + OFF_U))[(size_t)j * 128 + b] = acc;
}

// ---------------- attention (flash-blocked) + p_gen ----------------
__global__ __launch_bounds__(512) void k_attn(const float* __restrict__ pg_ctx,
                                              const float* __restrict__ pg_in,
                                              const float* __restrict__ pg_h,
                                              const float* __restrict__ pg_c,
                                              const float* __restrict__ pg_b,
                                              const int* __restrict__ E_idx,
                                              const unsigned char* __restrict__ C_pad,
                                              float* __restrict__ ws, int t) {
  __shared__ unsigned short tile[65536];  // 64 rows x 1024 bf16, 16B-block XOR swizzle
  __shared__ float u_lds[1032];
  __shared__ float scp[64][9];
  __shared__ float p_lds[64];
  __shared__ float sred[8];
  __shared__ float bc[2];
  int b = blockIdx.x, tau = threadIdx.x;
  int pr = t & 1;
  const float* U = (const float*)((char*)ws + OFF_U);
  u_lds[tau + (tau >> 7)] = U[(size_t)tau * 128 + b];
  {
    int x2 = tau + 512;
    u_lds[x2 + (x2 >> 7)] = U[(size_t)x2 * 128 + b];
  }
  float M = -3.0e38f, D = 0.f, c0 = 0.f, c1 = 0.f;
  const uint4* encb = (const uint4*)((char*)ws + OFF_ENC + (size_t)b * LC_ * 1024 * 2);
  float* SC = (float*)((char*)ws + OFF_SC);
  int l = tau >> 3, seg = tau & 7;
  for (int lb = 0; lb < 4; ++lb) {
    const uint4* src = encb + (size_t)lb * 64 * 128;
#pragma unroll
    for (int it = 0; it < 16; ++it) {
      int fl = it * 512 + tau;
      int r = fl >> 7, cb = fl & 127;
      ((uint4*)tile)[(r << 7) + (cb ^ (r & 7))] = src[fl];
    }
    __syncthreads();
    // scores partials
    float acc = 0.f;
#pragma unroll
    for (int ibv = 0; ibv < 16; ++ibv) {
      int blk = (seg * 16 + ibv) ^ (l & 7);
      const uint4 wv = *(const uint4*)&tile[(l << 10) + (blk << 3)];
      const float* up = &u_lds[seg * 128 + ibv * 8 + seg];
      acc += bfl(wv.x) * up[0] + bfh(wv.x) * up[1];
      acc += bfl(wv.y) * up[2] + bfh(wv.y) * up[3];
      acc += bfl(wv.z) * up[4] + bfh(wv.z) * up[5];
      acc += bfl(wv.w) * up[6] + bfh(wv.w) * up[7];
    }
    scp[l][seg] = acc;
    __syncthreads();
    if (tau < 64) {
      float s = scp[tau][0] + scp[tau][1] + scp[tau][2] + scp[tau][3]
              + scp[tau][4] + scp[tau][5] + scp[tau][6] + scp[tau][7];
      int gl = lb * 64 + tau;
      if (C_pad[b * LC_ + gl]) s = -3.0e38f;
      SC[b * 256 + gl] = s;
      float m = s;
      for (int o = 32; o; o >>= 1) m = fmaxf(m, __shfl_xor(m, o));
      float Mn = fmaxf(M, m);
      float pv = expf(s - Mn);
      p_lds[tau] = pv;
      float ds = pv;
      for (int o = 32; o; o >>= 1) ds += __shfl_xor(ds, o);
      if (tau == 0) { bc[0] = m; bc[1] = ds; }
    }
    __syncthreads();
    float Mn = fmaxf(M, bc[0]);
    float scale = expf(M - Mn);
    D = D * scale + bc[1];
    c0 *= scale; c1 *= scale;
    M = Mn;
    {
      int cb0 = tau >> 3, e0 = tau & 7;
      int cb1 = (tau + 512) >> 3;
#pragma unroll 8
      for (int l2 = 0; l2 < 64; ++l2) {
        float pv = p_lds[l2];
        float v0 = bfl((unsigned)tile[(l2 << 10) + (((cb0 ^ (l2 & 7)) << 3) | e0)]);
        float v1 = bfl((unsigned)tile[(l2 << 10) + (((cb1 ^ (l2 & 7)) << 3) | e0)]);
        c0 += pv * v0; c1 += pv * v1;
      }
    }
    __syncthreads();
  }
  float inv = 1.f / D;
  float x0 = c0 * inv, x1 = c1 * inv;
  float* CTX = (float*)((char*)ws + OFF_CTX);
  CTX[(size_t)tau * 128 + b] = x0;
  CTX[(size_t)(tau + 512) * 128 + b] = x1;
  // p_gen
  float pp = x0 * pg_ctx[tau] + x1 * pg_ctx[tau + 512];
  pp += ((const float*)((char*)ws + OFF_HDEC))[(size_t)(pr ^ 1) * HB_ + (size_t)tau * 128 + b] * pg_h[tau];
  pp += ((const float*)((char*)ws + OFF_CDEC))[(size_t)tau * 128 + b] * pg_c[tau];
  pp += ((const float*)((char*)ws + OFF_TOUT))[(size_t)pr * HB_ + (size_t)tau * 128 + b] * pg_in[128 + tau];
  for (int o = 32; o; o >>= 1) pp += __shfl_xor(pp, o);
  if ((tau & 63) == 0) sred[tau >> 6] = pp;
  __syncthreads();
  if (tau == 0) {
    float s = sred[0] + sred[1] + sred[2] + sred[3] + sred[4] + sred[5] + sred[6] + sred[7];
    int xid = E_idx[b * LE_ + t];
    s += pg_in[xid] + pg_b[0];
    float* MD = (float*)((char*)ws + OFF_MD);
    MD[256 + b] = sigm(s);
    MD[b] = M;
    MD[128 + b] = D;
  }
}

// ---------------- t_out = tanh([h,ctx] @ Wout^T) ----------------
__global__ __launch_bounds__(512) void k_wout(const float* __restrict__ Wout,
                                              float* __restrict__ ws, int t) {
  __shared__ float part[256];
  int tau = threadIdx.x;
  int kh = tau >> 8, q = tau & 255;
  int pp = blockIdx.x * 256 + q;       // 65536 = 512n * 128b
  int b = pp & 127, n = pp >> 7;
  int nn = __builtin_amdgcn_readfirstlane(n);
  int pr = t & 1;
  float acc = 0.f;
  if (kh == 0) {
    const float* w = Wout + (size_t)nn * 1536;
    const float* hp = (const float*)((char*)ws + OFF_HDEC) + (size_t)(pr ^ 1) * HB_ + b;
    for (int k = 0; k < 512; k += 4) {
      float4 W = *(const float4*)(w + k);
      acc += W.x * hp[(size_t)k * 128] + W.y * hp[(size_t)(k + 1) * 128]
           + W.z * hp[(size_t)(k + 2) * 128] + W.w * hp[(size_t)(k + 3) * 128];
    }
  } else {
    const float* w = Wout + (size_t)nn * 1536 + 512;
    const float* cp = (const float*)((char*)ws + OFF_CTX) + b;
    for (int k = 0; k < 1024; k += 4) {
      float4 W = *(const float4*)(w + k);
      acc += W.x * cp[(size_t)k * 128] + W.y * cp[(size_t)(k + 1) * 128]
           + W.z * cp[(size_t)(k + 2) * 128] + W.w * cp[(size_t)(k + 3) * 128];
    }
    part[q] = acc;
  }
  __syncthreads();
  if (kh == 0) {
    float s = acc + part[q];
    ((float*)((char*)ws + OFF_TOUT))[(size_t)(pr ^ 1) * HB_ + (size_t)n * 128 + b] = tanhf(s);
  }
}

// ---------------- final S4 (step 255) ----------------
__global__ __launch_bounds__(512) void k_final(const float* __restrict__ Wvocab,
                                               const int* __restrict__ E_idx,
                                               const int* __restrict__ C_idx,
                                               float* __restrict__ ws,
                                               float* __restrict__ out) {
  s4_body(ws, out, Wvocab, E_idx, C_idx, blockIdx.x, 256);
}

// ---------------- host ----------------
extern "C" void kernel_launch(void* const* d_in, const int* in_sizes, int n_in,
                              void* d_out, int out_size, void* d_ws, size_t ws_size,
                              hipStream_t stream) {
  (void)in_sizes; (void)n_in; (void)out_size; (void)ws_size;
  const int* C_idx = (const int*)d_in[0];
  const int* E_idx = (const int*)d_in[1];
  const unsigned char* C_pad = (const unsigned char*)d_in[2];
  const float* eWihF = (const float*)d_in[3];
  const float* eWhhF = (const float*)d_in[4];
  const float* ebF   = (const float*)d_in[5];
  const float* eWihB = (const float*)d_in[6];
  const float* eWhhB = (const float*)d_in[7];
  const float* ebB   = (const float*)d_in[8];
  const float* dWih  = (const float*)d_in[9];
  const float* dWhh  = (const float*)d_in[10];
  const float* db    = (const float*)d_in[11];
  const float* Wh    = (const float*)d_in[12];
  const float* Wc    = (const float*)d_in[13];
  const float* Wattn = (const float*)d_in[14];
  const float* Wout  = (const float*)d_in[15];
  const float* Wvoc  = (const float*)d_in[16];
  const float* pgc   = (const float*)d_in[17];
  const float* pgi   = (const float*)d_in[18];
  const float* pgh   = (const float*)d_in[19];
  const float* pgcc  = (const float*)d_in[20];
  const float* pgb   = (const float*)d_in[21];
  float* ws = (float*)d_ws;
  float* out = (float*)d_out;

  // zero recurrent init state: h_enc (both dirs/parities) + c_enc ; t_out (both parities)
  hipMemsetAsync((char*)d_ws + OFF_HENC, 0, 6 * HB_ * 4, stream);
  hipMemsetAsync((char*)d_ws + OFF_TOUT, 0, 2 * HB_ * 4, stream);

  k_pre<<<512, 256, 0, stream>>>(eWihF, eWihB, dWih, Wattn, ws);
  for (int t = 0; t < 256; ++t)
    k_enc<<<256, 512, 0, stream>>>(eWhhF, eWhhB, ebF, ebB, C_idx, ws, t);
  k_h0c0<<<256, 512, 0, stream>>>(Wh, Wc, ws);
  for (int t = 0; t < 256; ++t) {
    k_dgates<<<384, 512, 0, stream>>>(dWih, dWhh, db, Wvoc, E_idx, C_idx, ws, out, t);
    k_u<<<256, 512, 0, stream>>>(nullptr, ws, t);
    k_attn<<<128, 512, 0, stream>>>(pgc, pgi, pgh, pgcc, pgb, E_idx, C_pad, ws, t);
    k_wout<<<256, 512, 0, stream>>>(Wout, ws, t);
  }
  k_final<<<128, 512, 0, stream>>>(Wvoc, E_idx, C_idx, ws, out);
}